// Round 4
// baseline (312.849 us; speedup 1.0000x reference)
//
#include <hip/hip_runtime.h>
#include <hip/hip_bf16.h>
#include <math.h>

typedef float  f32x4  __attribute__((ext_vector_type(4)));
typedef short  bf16x4 __attribute__((ext_vector_type(4)));
typedef __bf16 bfv4   __attribute__((ext_vector_type(4)));

#define B_    16
#define S_    4096
#define D_    256
#define CK_   16                 // chunk length
#define NC_   (S_ / CK_)         // 256 chunks
#define NP_   (NC_ / 2)          // 128 fused pairs (32-row superchunks)
#define PBLOB_ 1664              // 512 Ta + 512 Tb + 512 Gx (bf16) + 64 ca + 64 cb (f32)
#define W_    8                  // waves per main block (column split)
#define RW_   6                  // reducer waves == reduced quantities

// ---------------- helpers
__device__ __forceinline__ f32x4 mfma_bf16(bf16x4 a, bf16x4 b, f32x4 c) {
#if defined(__has_builtin) && __has_builtin(__builtin_amdgcn_mfma_f32_16x16x16bf16_1k)
    return __builtin_amdgcn_mfma_f32_16x16x16bf16_1k(a, b, c, 0, 0, 0);
#else
    f32x4 d;
    asm("v_mfma_f32_16x16x16_bf16 %0, %1, %2, %3" : "=v"(d) : "v"(a), "v"(b), "v"(c));
    return d;
#endif
}
__device__ __forceinline__ bf16x4 pk4(f32x4 v) {
    bfv4 h;
    h[0] = (__bf16)v[0]; h[1] = (__bf16)v[1]; h[2] = (__bf16)v[2]; h[3] = (__bf16)v[3];
    return __builtin_bit_cast(bf16x4, h);
}
__device__ __forceinline__ f32x4 up4(bf16x4 h) {
    f32x4 r;
    r[0] = __uint_as_float(((unsigned)(unsigned short)h[0]) << 16);
    r[1] = __uint_as_float(((unsigned)(unsigned short)h[1]) << 16);
    r[2] = __uint_as_float(((unsigned)(unsigned short)h[2]) << 16);
    r[3] = __uint_as_float(((unsigned)(unsigned short)h[3]) << 16);
    return r;
}

// ---------------- prepass: one 64-thread wave per (b, pair). (R1/R3-verified)
__global__ __launch_bounds__(64) void ldm_prep(
    const float* __restrict__ x,
    const float* __restrict__ eta_raw,
    const float* __restrict__ alpha_raw,
    unsigned char* __restrict__ blob)
{
    const int lane = threadIdx.x;
    const int b = blockIdx.x >> 7;            // NP_ = 128
    const int p = blockIdx.x & (NP_ - 1);
    const int l15 = lane & 15;
    const int q   = lane >> 4;

    __shared__ float Ga[256], Gb[256], Gxs[256];
    __shared__ float csh[32];
    __shared__ float Ts[2][256];

    const float* xa = x + ((size_t)b * S_ + (size_t)p * 32 + l15) * D_ + q * 4;
    const float* xc = xa + 16 * D_;           // chunk b rows

    const f32x4 z = {0,0,0,0};
    f32x4 ga1=z, ga2=z, ga3=z, gb1=z, gb2=z, gb3=z, gx1=z, gx2=z, gx3=z;
    #pragma unroll 4
    for (int kb = 0; kb < 16; ++kb) {
        f32x4 va = *(const f32x4*)(xa + kb * 16);
        f32x4 vb = *(const f32x4*)(xc + kb * 16);
        bf16x4 ha = pk4(va), la = pk4(va - up4(ha));
        bf16x4 hb = pk4(vb), lb = pk4(vb - up4(hb));
        ga1 = mfma_bf16(ha, ha, ga1);
        ga2 = mfma_bf16(ha, la, ga2);
        ga3 = mfma_bf16(la, ha, ga3);
        gb1 = mfma_bf16(hb, hb, gb1);
        gb2 = mfma_bf16(hb, lb, gb2);
        gb3 = mfma_bf16(lb, hb, gb3);
        gx1 = mfma_bf16(hb, ha, gx1);         // Gx[t_b][t_a] = x_b . x_a
        gx2 = mfma_bf16(hb, la, gx2);
        gx3 = mfma_bf16(lb, ha, gx3);
    }
    f32x4 ga = (ga1 + ga2) + ga3;             // C layout: lane holds G[q*4+r][l15]
    f32x4 gb = (gb1 + gb2) + gb3;
    f32x4 gx = (gx1 + gx2) + gx3;
    *(f32x4*)(&Ga[l15 * 16 + q * 4]) = ga;    // symmetric: transposed store ok
    *(f32x4*)(&Gb[l15 * 16 + q * 4]) = gb;
    #pragma unroll
    for (int r = 0; r < 4; ++r) Gxs[(q * 4 + r) * 16 + l15] = gx[r];
    __syncthreads();

    const float eta   = 0.2f / (1.0f + expf(-eta_raw[0]));
    const float alpha = 0.5f + 0.5f / (1.0f + expf(-alpha_raw[0]));
    if (lane < 32) {
        const float* G = (lane < 16) ? Ga : Gb;
        float gtt = G[l15 * 17];
        float n   = fmaxf(sqrtf(gtt), 1e-6f);
        float inv = 1.0f / n;
        csh[lane] = eta * (1.0f - inv) * inv / alpha;
    }
    __syncthreads();

    if (lane < 32) {                          // column-parallel forward substitution x2
        const int j = l15;
        const float* G  = (lane < 16) ? Ga : Gb;
        const float* cp = (lane < 16) ? csh : csh + 16;
        float cr[16];
        #pragma unroll
        for (int k = 0; k < 16; ++k) cr[k] = cp[k];
        float Tcol[16];
        Tcol[0] = 0.f;
        #pragma unroll
        for (int t = 1; t < 16; ++t) {
            float acc = cr[j] * G[t * 16 + j];
            #pragma unroll
            for (int k = 1; k < 15; ++k)
                if (k < t) acc += cr[k] * G[t * 16 + k] * Tcol[k];
            Tcol[t] = (t > j) ? acc : 0.f;
        }
        float* Tsj = Ts[lane >> 4];
        #pragma unroll
        for (int t = 0; t < 16; ++t) Tsj[t * 16 + j] = Tcol[t];
    }
    __syncthreads();

    unsigned char* bp = blob + (size_t)(b * NP_ + p) * PBLOB_;
    const int idx = l15 * 16 + q * 4;
    *(bf16x4*)(bp + idx * 2)        = pk4(*(const f32x4*)(&Ts[0][idx]));
    *(bf16x4*)(bp + 512 + idx * 2)  = pk4(*(const f32x4*)(&Ts[1][idx]));
    *(bf16x4*)(bp + 1024 + idx * 2) = pk4(*(const f32x4*)(&Gxs[idx]));
    if (lane < 32) ((float*)(bp + 1536))[lane] = csh[lane];
}

// ---------------- main scan: one 512-thread block (8 waves) per (batch, rowblk).
// Pipelined (R2 algebra, ds_write mechanics): body(j) pre-barrier computes pair
// j+1's STALE retrieval (vs M_{j-1}) + on-the-fly cross-Grams X_{j+1}X_j^T as
// per-wave partials -> ds_write. Post-barrier it reads pair j's six sums
// (reduced by waves 0-5 during body(j-1), so NO reduce round-trip on the
// critical path), corrects bb_true = a32*(stale + Cross*E_{j-1}), runs the
// fixup chain, updates master. Waves 0-5 reduce pair j+1's partials off-chain;
// waves 6/7 do the output stores.
__global__ __launch_bounds__(512) void ldm_main(
    const float* __restrict__ x,
    const float* __restrict__ Minit,
    const float* __restrict__ alpha_raw,
    const unsigned char* __restrict__ blob,
    float* __restrict__ out)
{
    const int tid    = threadIdx.x;
    const int lane   = tid & 63;
    const int w      = __builtin_amdgcn_readfirstlane(tid >> 6); // 0..7
    const int batch  = blockIdx.x >> 4;
    const int rowblk = blockIdx.x & 15;
    const int l15    = lane & 15;
    const int q      = lane >> 4;
    const int kcol0  = w * 32 + q * 4;

    __shared__ f32x4 parts[RW_][W_][64];      // 48 KB (single-buffered; B' protects)
    __shared__ f32x4 sums[2][RW_][64];        // 12 KB (parity)

    const float alpha = 0.5f + 0.5f / (1.0f + expf(-alpha_raw[0]));
    const float a2 = alpha * alpha, a4 = a2 * a2, a8 = a4 * a4, a16 = a8 * a8;
    const float a32 = a16 * a16;
    const float inv_a32 = 1.0f / a32;
    const float aq = (q == 0) ? 1.f : (q == 1) ? a4 : (q == 2) ? a8 : a8 * a4;
    const f32x4 apowA = { aq, aq * alpha, aq * a2, aq * a2 * alpha };
    const f32x4 apowB = apowA * a16;

    // identity B-fragment for transpose MFMA
    const int s = l15 - (q << 2);
    bf16x4 IB;
    IB[0] = (s == 0) ? (short)0x3F80 : (short)0;
    IB[1] = (s == 1) ? (short)0x3F80 : (short)0;
    IB[2] = (s == 2) ? (short)0x3F80 : (short)0;
    IB[3] = (s == 3) ? (short)0x3F80 : (short)0;

    const int mrow = rowblk * 16 + l15;
    f32x4 master[2];
    master[0] = *(const f32x4*)(Minit + (size_t)mrow * D_ + kcol0);
    master[1] = *(const f32x4*)(Minit + (size_t)mrow * D_ + kcol0 + 16);

    const float* xb = x + (size_t)batch * S_ * D_;
    const unsigned char* bb0 = blob + (size_t)batch * NP_ * PBLOB_;
    const int tfoff = (l15 * 16 + q * 4) * 2;

    struct Blob { bf16x4 Ta, Tb, Gx; f32x4 ca, cb; };
    Blob bA, bB;
    bf16x4 XA[4], XB[4];          // bf16 frags for pair j / j+1 (alternating)
    f32x4  Xf[4];                 // f32 in-flight (holds X(j+1) entering body(j))
    bf16x4 ea_prev = {0,0,0,0}, eb_prev = {0,0,0,0};
    const f32x4 zz = {0,0,0,0};

    // running pointers (no per-body 64-bit muls)
    const float* xr0 = xb + (size_t)l15 * D_ + kcol0;
    const float* xptr = xr0 + (size_t)2 * 32 * D_;     // -> X(2)
    const unsigned char* bptr = bb0 + PBLOB_;          // -> blob(1)
    float* outpj = out + (size_t)batch * S_ * D_ + rowblk * 16 + l15
                 + (size_t)q * 4 * D_;                 // chunk-a row base, body 0

    {   // ---------------- prologue: pair 0
        Xf[0] = *(const f32x4*)(xr0);                  // reuse Xf briefly for pair 0
        Xf[1] = *(const f32x4*)(xr0 + 16);
        Xf[2] = *(const f32x4*)(xr0 + 16 * D_);
        Xf[3] = *(const f32x4*)(xr0 + 16 * D_ + 16);
        XA[0] = pk4(Xf[0]); XA[1] = pk4(Xf[1]); XA[2] = pk4(Xf[2]); XA[3] = pk4(Xf[3]);
        const float* x1 = xr0 + 32 * D_;
        Xf[0] = *(const f32x4*)(x1);                   // pair 1 in-flight
        Xf[1] = *(const f32x4*)(x1 + 16);
        Xf[2] = *(const f32x4*)(x1 + 16 * D_);
        Xf[3] = *(const f32x4*)(x1 + 16 * D_ + 16);
        bA.Ta = *(const bf16x4*)(bb0 + tfoff);
        bA.Tb = *(const bf16x4*)(bb0 + 512 + tfoff);
        bA.Gx = *(const bf16x4*)(bb0 + 1024 + tfoff);
        bA.ca = *(const f32x4*)(bb0 + 1536 + q * 16);
        bA.cb = *(const f32x4*)(bb0 + 1600 + q * 16);
        // stale retrieval for pair 0 vs M_init, pre-divided by a32 so the
        // uniform in-loop bb = a32*(stale+corr) is exact (R2-verified trick).
        bf16x4 m0b = pk4(master[0]), m1b = pk4(master[1]);
        f32x4 ra = mfma_bf16(XA[1], m1b, mfma_bf16(XA[0], m0b, zz));
        f32x4 rb = mfma_bf16(XA[3], m1b, mfma_bf16(XA[2], m0b, zz));
        ra *= inv_a32; rb *= inv_a32;
        parts[0][w][lane] = ra;
        parts[1][w][lane] = rb;
        parts[2][w][lane] = zz;
        parts[3][w][lane] = zz;
        parts[4][w][lane] = zz;
        parts[5][w][lane] = zz;
        __syncthreads();
        if (w < RW_) {                                 // reduce pair 0 -> sums[0]
            f32x4 u0 = parts[w][0][lane] + parts[w][1][lane];
            f32x4 u1 = parts[w][2][lane] + parts[w][3][lane];
            f32x4 u2 = parts[w][4][lane] + parts[w][5][lane];
            f32x4 u3 = parts[w][6][lane] + parts[w][7][lane];
            sums[0][w][lane] = (u0 + u1) + (u2 + u3);
        }
        __syncthreads();   // protect parts before body(0) P1 overwrites them
    }

    auto body = [&](int j, bf16x4 (&Xc)[4], bf16x4 (&Xn)[4], Blob& bc, Blob& bn) {
        // ---- P1: partials for pair j+1 (stale vs M_{j-1}) + cross-Grams + t-frags
        Xn[0] = pk4(Xf[0]); Xn[1] = pk4(Xf[1]); Xn[2] = pk4(Xf[2]); Xn[3] = pk4(Xf[3]);
        Xf[0] = *(const f32x4*)(xptr);                 // prefetch X(j+2)
        Xf[1] = *(const f32x4*)(xptr + 16);
        Xf[2] = *(const f32x4*)(xptr + 16 * D_);
        Xf[3] = *(const f32x4*)(xptr + 16 * D_ + 16);
        if (j < NP_ - 3) xptr += 32 * D_;
        bn.Ta = *(const bf16x4*)(bptr + tfoff);        // prefetch blob(j+1)
        bn.Tb = *(const bf16x4*)(bptr + 512 + tfoff);
        bn.Gx = *(const bf16x4*)(bptr + 1024 + tfoff);
        bn.ca = *(const f32x4*)(bptr + 1536 + q * 16);
        bn.cb = *(const f32x4*)(bptr + 1600 + q * 16);
        if (j < NP_ - 2) bptr += PBLOB_;

        bf16x4 m0b = pk4(master[0]), m1b = pk4(master[1]);
        f32x4 ra = mfma_bf16(Xn[1], m1b, mfma_bf16(Xn[0], m0b, zz));
        f32x4 rb = mfma_bf16(Xn[3], m1b, mfma_bf16(Xn[2], m0b, zz));
        // cross-Gram partials; C-layout == A-frag of Cross (R2-verified)
        f32x4 caa = mfma_bf16(Xc[1], Xn[1], mfma_bf16(Xc[0], Xn[0], zz));
        f32x4 cab = mfma_bf16(Xc[3], Xn[1], mfma_bf16(Xc[2], Xn[0], zz));
        f32x4 cba = mfma_bf16(Xc[1], Xn[3], mfma_bf16(Xc[0], Xn[2], zz));
        f32x4 cbb = mfma_bf16(Xc[3], Xn[3], mfma_bf16(Xc[2], Xn[2], zz));
        // transpose frags for pair j (X^T, own cols)
        bf16x4 t0a = pk4(mfma_bf16(Xc[0], IB, zz));
        bf16x4 t1a = pk4(mfma_bf16(Xc[1], IB, zz));
        bf16x4 t0b = pk4(mfma_bf16(Xc[2], IB, zz));
        bf16x4 t1b = pk4(mfma_bf16(Xc[3], IB, zz));
        parts[0][w][lane] = ra;
        parts[1][w][lane] = rb;
        parts[2][w][lane] = caa;
        parts[3][w][lane] = cab;
        parts[4][w][lane] = cba;
        parts[5][w][lane] = cbb;
        __syncthreads();                               // B(j)

        // ---- P2: pair j's sums are ALREADY reduced (during body j-1)
        const int pc = j & 1, pn = pc ^ 1;
        f32x4 bbA = sums[pc][0][lane];
        f32x4 bbB = sums[pc][1][lane];
        f32x4 SAA = sums[pc][2][lane];
        f32x4 SAB = sums[pc][3][lane];
        f32x4 SBA = sums[pc][4][lane];
        f32x4 SBB = sums[pc][5][lane];
        // reducer staging reads issued now, combined after the fixup (off-chain)
        f32x4 rp0, rp1, rp2, rp3, rp4, rp5, rp6, rp7;
        if (w < RW_) {
            rp0 = parts[w][0][lane]; rp1 = parts[w][1][lane];
            rp2 = parts[w][2][lane]; rp3 = parts[w][3][lane];
            rp4 = parts[w][4][lane]; rp5 = parts[w][5][lane];
            rp6 = parts[w][6][lane]; rp7 = parts[w][7][lane];
        }
        bf16x4 FAA = pk4(SAA), FAB = pk4(SAB), FBA = pk4(SBA), FBB = pk4(SBB);
        // bb_true = a32 * (stale + Cross_a*E_a_prev + Cross_b*E_b_prev)
        bbA = mfma_bf16(FAA, ea_prev, bbA);
        bbA = mfma_bf16(FAB, eb_prev, bbA);
        bbA *= a32;
        bbB = mfma_bf16(FBA, ea_prev, bbB);
        bbB = mfma_bf16(FBB, eb_prev, bbB);
        bbB *= a32;
        // chunk a fixup
        f32x4 da = mfma_bf16(bc.Ta, pk4(bbA), bbA);
        if (w == 6) {
            #pragma unroll
            for (int r = 0; r < 4; ++r) outpj[r * D_] = da[r] * apowA[r];
        }
        bf16x4 ea = pk4(da * bc.ca);
        // chunk b in-pair correction + fixup
        bbB = mfma_bf16(bc.Gx, ea, bbB);
        f32x4 db = mfma_bf16(bc.Tb, pk4(bbB), bbB);
        if (w == 7) {
            float* ob = outpj + 16 * D_;
            #pragma unroll
            for (int r = 0; r < 4; ++r) ob[r * D_] = db[r] * apowB[r];
        }
        bf16x4 eb = pk4(db * bc.cb);
        // master += X_a^T E_a + X_b^T E_b, then *alpha^32
        master[0] = mfma_bf16(t0a, ea, master[0]);
        master[0] = mfma_bf16(t0b, eb, master[0]) * a32;
        master[1] = mfma_bf16(t1a, ea, master[1]);
        master[1] = mfma_bf16(t1b, eb, master[1]) * a32;
        // reducer finish: pair j+1 sums for next body
        if (w < RW_) {
            f32x4 u0 = rp0 + rp1, u1 = rp2 + rp3, u2 = rp4 + rp5, u3 = rp6 + rp7;
            sums[pn][w][lane] = (u0 + u1) + (u2 + u3);
        }
        ea_prev = ea; eb_prev = eb;
        outpj += 32 * D_;
        __syncthreads();                               // B'(j): parts/sums WAR guard
    };

    for (int j = 0; j < NP_; j += 2) {
        body(j,     XA, XB, bA, bB);
        body(j + 1, XB, XA, bB, bA);
    }

    // M_final -> second output region [B, D, D]
    float* Mout = out + (size_t)B_ * S_ * D_
                + ((size_t)batch * D_ + mrow) * D_;
    *(f32x4*)(Mout + kcol0)      = master[0];
    *(f32x4*)(Mout + kcol0 + 16) = master[1];
}

extern "C" void kernel_launch(void* const* d_in, const int* in_sizes, int n_in,
                              void* d_out, int out_size, void* d_ws, size_t ws_size,
                              hipStream_t stream) {
    const float* x         = (const float*)d_in[0];
    const float* Minit     = (const float*)d_in[1];
    const float* eta_raw   = (const float*)d_in[2];
    const float* alpha_raw = (const float*)d_in[3];
    float* out = (float*)d_out;
    unsigned char* blob = (unsigned char*)d_ws;   // B_*NP_*1664 = 3.4 MB

    hipLaunchKernelGGL(ldm_prep, dim3(B_ * NP_), dim3(64), 0, stream,
                       x, eta_raw, alpha_raw, blob);
    hipLaunchKernelGGL(ldm_main, dim3(B_ * 16), dim3(512), 0, stream,
                       x, Minit, alpha_raw, blob, out);
}